// Round 1
// baseline (249.668 us; speedup 1.0000x reference)
//
#include <hip/hip_runtime.h>
#include <hip/hip_bf16.h>

// B=8192 rows, N=4096 omegas/row, W=1000 bins, L=101 Legendre terms.
// Exact simplifications:
//   * pdf normalization cancels in grad/pdf -> skipped
//   * gauss branch of _pdf_no_cosine never selected when pdf is used
//     (needs sigma>0.6>0.2) -> skipped
//   * sigma<=0.6 rows are pure elementwise -omega/sigma^2 (pdf unused)
//   * series terms with 0.5*l*(l+1)*sigma^2 > 44 underflow vs pdf scale
//     (sigma>0.6 -> lmax <= 17); truncation error < 1e-14 abs.
// Structure: 1 row per block (grid=8192 -> 4 residency waves/CU so the
// latency-chained table build of later blocks overlaps streaming of earlier
// ones). LDS ~4.2 KB. Nontemporal stores keep omegas resident in LLC.

#define L_TERMS 101
#define W_BINS 1000
#define N_COLS 4096
#define TPB 256
#define TRANS_STRIDE 1024   // padded transpose row stride (w0+3 <= 1023 in-bounds)
#define PAD_W 1004          // shifted pdf table: tab[k] = p[k-1], k=1..1000
#define GRAD_T 0.6f
#define LMAX_CAP 32         // formula gives <=17 for sigma>0.6

typedef float v4f __attribute__((ext_vector_type(4)));

// ---------------------------------------------------------------------------
// Kernel 1: transpose sine_terms [1000][101] -> sine_t [101][1024] (padded)
__global__ __launch_bounds__(128) void transpose_sine(
    const float* __restrict__ sine, float* __restrict__ sine_t) {
  int w = blockIdx.x;   // 0..999
  int t = threadIdx.x;  // 0..127
  if (t < L_TERMS) sine_t[(size_t)t * TRANS_STRIDE + w] = sine[(size_t)w * L_TERMS + t];
}

// ---------------------------------------------------------------------------
template <bool TRANS>
__global__ __launch_bounds__(TPB, 8) void igso3_main(
    const float* __restrict__ sigmas,
    const float* __restrict__ omegas,
    const float* __restrict__ omega_grid,
    const float* __restrict__ sine_src,  // TRANS ? [101][1024] : [1000][101]
    float* __restrict__ out) {
  __shared__ float s_exp[LMAX_CAP];
  __shared__ float s_pdf[PAD_W];   // tab[k] = p[k-1]; tab[0]=p[0], tab[1001]=p[998]

  const int tid = threadIdx.x;
  const int b = blockIdx.x;
  const float s = sigmas[b];       // uniform -> scalar load

  const float bw = omega_grid[1] - omega_grid[0];
  const float inv_bw = 1.0f / bw;  // IEEE, computed once

  const v4f* __restrict__ om4 = (const v4f*)(omegas + (size_t)b * N_COLS);
  v4f* __restrict__ out4 = (v4f*)(out + (size_t)b * N_COLS);

  if (s <= GRAD_T) {
    // pure elementwise row: -omega / sigma^2
    const float inv_s2 = __builtin_amdgcn_rcpf(s * s);
    v4f om[4];
#pragma unroll
    for (int k = 0; k < 4; ++k) om[k] = om4[k * TPB + tid];
#pragma unroll
    for (int k = 0; k < 4; ++k) {
      v4f r = om[k] * (-inv_s2);
      __builtin_nontemporal_store(r, &out4[k * TPB + tid]);
    }
    return;   // block-uniform: no barrier ever executed in this block
  }

  // ---- table build (block-uniform path) ----
  // smallest l with 0.5*l*(l+1)*s^2 >= 44  ->  l >= (-1+sqrt(1+352/s^2))/2
  float le = ceilf((-1.0f + sqrtf(1.0f + 352.0f / (s * s))) * 0.5f) + 1.0f;
  int lmax = min((int)le, LMAX_CAP);

  if (tid < lmax) s_exp[tid] = __expf(-0.5f * (float)(tid * (tid + 1)) * s * s);
  __syncthreads();

  const int w0 = tid * 4;
  float acc[4] = {0.0f, 0.0f, 0.0f, 0.0f};
  if (TRANS) {
    for (int l = 0; l < lmax; ++l) {
      v4f sv = *(const v4f*)(sine_src + (size_t)l * TRANS_STRIDE + w0);
      float e = s_exp[l];   // same-address LDS broadcast
      acc[0] = fmaf(e, sv.x, acc[0]);
      acc[1] = fmaf(e, sv.y, acc[1]);
      acc[2] = fmaf(e, sv.z, acc[2]);
      acc[3] = fmaf(e, sv.w, acc[3]);
    }
  } else if (w0 < W_BINS) {
    for (int l = 0; l < lmax; ++l) {
      float e = s_exp[l];
#pragma unroll
      for (int j = 0; j < 4; ++j)
        acc[j] = fmaf(e, sine_src[(size_t)(w0 + j) * L_TERMS + l], acc[j]);
    }
  }
  if (w0 < W_BINS) {
#pragma unroll
    for (int j = 0; j < 4; ++j) s_pdf[w0 + 1 + j] = acc[j];
    if (tid == 0) s_pdf[0] = acc[0];          // pad left  = p[0]
    if (w0 == 996) s_pdf[1001] = acc[2];      // pad right = p[998]
  }
  __syncthreads();

  // ---- streaming gather: 4 float4 per thread, loads hoisted ----
  v4f om[4];
#pragma unroll
  for (int k = 0; k < 4; ++k) om[k] = om4[k * TPB + tid];
#pragma unroll
  for (int k = 0; k < 4; ++k) {
    float o[4] = {om[k].x, om[k].y, om[k].z, om[k].w};
    float rv[4];
#pragma unroll
    for (int j = 0; j < 4; ++j) {
      // omega >= 0 -> q >= 0.5 -> int-cast == floor; idx >= 0 guaranteed
      int idx = (int)fmaf(o[j], inv_bw, 0.5f);
      idx = min(idx, 1000);
      float shift = fmaf(-((float)idx + 0.5f), bw, o[j]);
      float left  = s_pdf[idx];        // ds_read2_b32 pair
      float right = s_pdf[idx + 1];
      float grad = (right - left) * inv_bw;
      float accu = fmaf(shift, grad, left);
      rv[j] = grad * __builtin_amdgcn_rcpf(accu);
    }
    v4f res = {rv[0], rv[1], rv[2], rv[3]};
    __builtin_nontemporal_store(res, &out4[k * TPB + tid]);
  }
}

// ---------------------------------------------------------------------------
extern "C" void kernel_launch(void* const* d_in, const int* in_sizes, int n_in,
                              void* d_out, int out_size, void* d_ws, size_t ws_size,
                              hipStream_t stream) {
  const float* sigmas     = (const float*)d_in[0];
  const float* omegas     = (const float*)d_in[1];
  const float* omega_grid = (const float*)d_in[2];
  // d_in[3] = ls (unused)
  const float* sine_terms = (const float*)d_in[4];
  float* out = (float*)d_out;

  const int B = in_sizes[0];  // 8192 -> one block per row

  const size_t need = (size_t)L_TERMS * TRANS_STRIDE * sizeof(float);  // ~404 KB
  if (ws_size >= need) {
    transpose_sine<<<W_BINS, 128, 0, stream>>>(sine_terms, (float*)d_ws);
    igso3_main<true><<<B, TPB, 0, stream>>>(sigmas, omegas, omega_grid,
                                            (const float*)d_ws, out);
  } else {
    igso3_main<false><<<B, TPB, 0, stream>>>(sigmas, omegas, omega_grid,
                                             sine_terms, out);
  }
}

// Round 3
// 246.318 us; speedup vs baseline: 1.0136x; 1.0136x over previous
//
#include <hip/hip_runtime.h>
#include <hip/hip_bf16.h>

// B=8192 rows, N=4096 omegas/row, W=1000 bins, L=101 Legendre terms.
// Exact simplifications:
//   * pdf normalization cancels in grad/pdf -> skipped
//   * gauss branch of _pdf_no_cosine never selected when pdf is used
//     (needs sigma>0.6>0.2) -> skipped
//   * sigma<=0.6 rows are pure elementwise -omega/sigma^2 (pdf unused)
//   * series terms beyond l=16 underflow vs pdf scale for sigma>0.6
//     (0.5*17*18*0.36 = 55 > 44) -> FIXED L=17 term loop, fully unrolled.
//     Superset of the old dynamic lmax<=17 -> strictly more accurate.
// Round-2/3 structure change (latency theory): per-block serial chain was
//   table-build(serial L2 loads) -> barrier -> om HBM loads -> gather.
// Now: om loads issue FIRST (HBM latency overlaps table build), exps are
// recomputed per-thread (kills s_exp LDS + one barrier), l-loop is
// compile-time 17 so all 17 L2 loads pipeline.
// Round-3 FIX: readfirstlane on float was silently value-converting
// float->int (e[l>0] became 0 -> series rows all-zero). Bitcast through
// int for the SGPR pin: __int_as_float(rfl(__float_as_int(ev))).

#define L_TERMS 101
#define W_BINS 1000
#define N_COLS 4096
#define TPB 256
#define TRANS_STRIDE 1024   // padded transpose row stride (w0+3 <= 1023 in-bounds)
#define PAD_W 1004          // shifted pdf table: tab[k] = p[k-1], k=1..1000
#define GRAD_T 0.6f
#define L_FIX 17            // fixed term count, exact for sigma > 0.6

typedef float v4f __attribute__((ext_vector_type(4)));

// ---------------------------------------------------------------------------
// Kernel 1: transpose sine_terms [1000][101] -> sine_t [101][1024] (padded)
__global__ __launch_bounds__(128) void transpose_sine(
    const float* __restrict__ sine, float* __restrict__ sine_t) {
  int w = blockIdx.x;   // 0..999
  int t = threadIdx.x;  // 0..127
  if (t < L_TERMS) sine_t[(size_t)t * TRANS_STRIDE + w] = sine[(size_t)w * L_TERMS + t];
}

// ---------------------------------------------------------------------------
template <bool TRANS>
__global__ __launch_bounds__(TPB, 6) void igso3_main(
    const float* __restrict__ sigmas,
    const float* __restrict__ omegas,
    const float* __restrict__ omega_grid,
    const float* __restrict__ sine_src,  // TRANS ? [101][1024] : [1000][101]
    float* __restrict__ out) {
  __shared__ float s_pdf[PAD_W];   // tab[k] = p[k-1]; tab[0]=p[0], tab[1001]=p[998]

  const int tid = threadIdx.x;
  const int b = blockIdx.x;

  const v4f* __restrict__ om4 = (const v4f*)(omegas + (size_t)b * N_COLS);
  v4f* __restrict__ out4 = (v4f*)(out + (size_t)b * N_COLS);

  // Issue the row's global loads FIRST: their HBM latency overlaps the
  // table build below (or is immediately consumed in the gaussian path).
  v4f om[4];
#pragma unroll
  for (int k = 0; k < 4; ++k) om[k] = om4[k * TPB + tid];

  const float s = sigmas[b];       // uniform -> scalar load
  const float bw = omega_grid[1] - omega_grid[0];
  const float inv_bw = 1.0f / bw;  // IEEE, computed once

  if (s <= GRAD_T) {
    // pure elementwise row: -omega / sigma^2
    const float inv_s2 = __builtin_amdgcn_rcpf(s * s);
#pragma unroll
    for (int k = 0; k < 4; ++k) {
      v4f r = om[k] * (-inv_s2);
      __builtin_nontemporal_store(r, &out4[k * TPB + tid]);
    }
    return;   // block-uniform: no barrier ever executed in this block
  }

  // ---- table build (block-uniform path) ----
  // e[l] = exp(-0.5*l*(l+1)*s^2), wave-uniform; recomputed per-thread
  // (~17 v_exp) instead of LDS broadcast: removes one __syncthreads from
  // the serial chain. Bitcast readfirstlane pins them in SGPRs.
  float e[L_FIX];
  const float ns2 = -0.5f * s * s;
#pragma unroll
  for (int l = 0; l < L_FIX; ++l) {
    float ev = __expf(ns2 * (float)(l * (l + 1)));
    e[l] = __int_as_float(__builtin_amdgcn_readfirstlane(__float_as_int(ev)));
  }

  const int w0 = tid * 4;
  float acc[4] = {0.0f, 0.0f, 0.0f, 0.0f};
  if (TRANS) {
#pragma unroll
    for (int l = 0; l < L_FIX; ++l) {
      v4f sv = *(const v4f*)(sine_src + (size_t)l * TRANS_STRIDE + w0);
      acc[0] = fmaf(e[l], sv.x, acc[0]);
      acc[1] = fmaf(e[l], sv.y, acc[1]);
      acc[2] = fmaf(e[l], sv.z, acc[2]);
      acc[3] = fmaf(e[l], sv.w, acc[3]);
    }
  } else if (w0 < W_BINS) {
#pragma unroll
    for (int l = 0; l < L_FIX; ++l) {
#pragma unroll
      for (int j = 0; j < 4; ++j)
        acc[j] = fmaf(e[l], sine_src[(size_t)(w0 + j) * L_TERMS + l], acc[j]);
    }
  }
  if (w0 < W_BINS) {
#pragma unroll
    for (int j = 0; j < 4; ++j) s_pdf[w0 + 1 + j] = acc[j];
    if (tid == 0) s_pdf[0] = acc[0];          // pad left  = p[0]
    if (w0 == 996) s_pdf[1001] = acc[2];      // pad right = p[998]
  }
  __syncthreads();

  // ---- streaming gather: 4 float4 per thread, loads already in registers ----
#pragma unroll
  for (int k = 0; k < 4; ++k) {
    float o[4] = {om[k].x, om[k].y, om[k].z, om[k].w};
    float rv[4];
#pragma unroll
    for (int j = 0; j < 4; ++j) {
      // omega >= 0 -> q >= 0.5 -> int-cast == floor; idx >= 0 guaranteed
      int idx = (int)fmaf(o[j], inv_bw, 0.5f);
      idx = min(idx, 1000);
      float shift = fmaf(-((float)idx + 0.5f), bw, o[j]);
      float left  = s_pdf[idx];        // ds_read2_b32 pair
      float right = s_pdf[idx + 1];
      float grad = (right - left) * inv_bw;
      float accu = fmaf(shift, grad, left);
      rv[j] = grad * __builtin_amdgcn_rcpf(accu);
    }
    v4f res = {rv[0], rv[1], rv[2], rv[3]};
    __builtin_nontemporal_store(res, &out4[k * TPB + tid]);
  }
}

// ---------------------------------------------------------------------------
extern "C" void kernel_launch(void* const* d_in, const int* in_sizes, int n_in,
                              void* d_out, int out_size, void* d_ws, size_t ws_size,
                              hipStream_t stream) {
  const float* sigmas     = (const float*)d_in[0];
  const float* omegas     = (const float*)d_in[1];
  const float* omega_grid = (const float*)d_in[2];
  // d_in[3] = ls (unused)
  const float* sine_terms = (const float*)d_in[4];
  float* out = (float*)d_out;

  const int B = in_sizes[0];  // 8192 -> one block per row

  const size_t need = (size_t)L_TERMS * TRANS_STRIDE * sizeof(float);  // ~404 KB
  if (ws_size >= need) {
    transpose_sine<<<W_BINS, 128, 0, stream>>>(sine_terms, (float*)d_ws);
    igso3_main<true><<<B, TPB, 0, stream>>>(sigmas, omegas, omega_grid,
                                            (const float*)d_ws, out);
  } else {
    igso3_main<false><<<B, TPB, 0, stream>>>(sigmas, omegas, omega_grid,
                                             sine_terms, out);
  }
}